// Round 3
// baseline (302.608 us; speedup 1.0000x reference)
//
#include <hip/hip_runtime.h>

#define NN 2048
#define BB 4
#define DD 512
#define HH 8
#define DHH 64
#define RR 8192   // BB*NN

typedef __attribute__((ext_vector_type(8))) __bf16 bf16x8;
typedef __attribute__((ext_vector_type(4))) float f32x4;
typedef __attribute__((ext_vector_type(2))) unsigned int u32x2;
typedef __attribute__((ext_vector_type(4))) unsigned int u32x4;

static __device__ __forceinline__ unsigned short f2bf(float f) {
  unsigned u = __builtin_bit_cast(unsigned, f);
  u += 0x7fffu + ((u >> 16) & 1u);
  return (unsigned short)(u >> 16);
}

// swizzled ushort index into a [rows][32] bf16 LDS tile (8-element granules)
static __device__ __forceinline__ int swz(int row, int col) {
  return (row * 32 + col) ^ (((row >> 1) & 3) << 3);
}

// ---------------- cast + reorder inputs: x,kv (N,B,D) fp32 -> [b*2048+n][D] bf16
__global__ __launch_bounds__(256) void cast_in_kernel(
    const float* __restrict__ x, const float* __restrict__ kv,
    unsigned short* __restrict__ xb, unsigned short* __restrict__ kvb) {
  const float* src = blockIdx.y ? kv : x;
  unsigned short* dst = blockIdx.y ? kvb : xb;
  int t = blockIdx.x * 256 + threadIdx.x;
  int o0 = t * 8;                       // output flat index, [b][n][d]
  int d = o0 & 511;
  int n = (o0 >> 9) & 2047;
  int b = o0 >> 20;
  const float* s = src + ((size_t)(n * BB + b) << 9) + d;
  f32x4 v0 = *(const f32x4*)s;
  f32x4 v1 = *(const f32x4*)(s + 4);
  union { unsigned short us[8]; u32x4 v; } o;
#pragma unroll
  for (int i = 0; i < 4; ++i) { o.us[i] = f2bf(v0[i]); o.us[4 + i] = f2bf(v1[i]); }
  *(u32x4*)(dst + o0) = o.v;
}

// ---------------- cast + transpose weights: W[k][o] fp32 -> WT[o][k] bf16 (512x512 each)
__global__ __launch_bounds__(256) void cast_w_kernel(
    const float* __restrict__ Wq, const float* __restrict__ Wkv, const float* __restrict__ Wo,
    unsigned short* __restrict__ WqT, unsigned short* __restrict__ WkvT, unsigned short* __restrict__ WoT) {
  const float* W = (blockIdx.y == 0) ? Wq : (blockIdx.y == 1) ? Wkv : Wo;
  unsigned short* WT = (blockIdx.y == 0) ? WqT : (blockIdx.y == 1) ? WkvT : WoT;
  int idx = blockIdx.x * 256 + threadIdx.x;  // 0..262143
  int o = idx & 511;
  int k = idx >> 9;
  WT[(size_t)o * 512 + k] = f2bf(W[(size_t)k * 512 + o]);
}

// ---------------- shared 128x128-tile GEMM, K=512, bf16 MFMA
// EPI 0: per-head LN -> q bf16 [b][h][n][64]
// EPI 1: cast -> kvp bf16 [b][h][m][64] AND kvpT bf16 [b][h][64][m]
// EPI 2: + bias -> fp32 [r][512]
template <int EPI>
__global__ __launch_bounds__(256) void gemm_kernel(
    const unsigned short* __restrict__ A,   // [8192][512] bf16
    const unsigned short* __restrict__ WT,  // [512 out][512 k] bf16
    const float* __restrict__ g,            // ln gamma (64) | bias (512)
    const float* __restrict__ beta,         // ln beta (64)
    unsigned short* __restrict__ out_bf,
    unsigned short* __restrict__ out_bf2,
    float* __restrict__ out_f32) {
  __shared__ unsigned short At[128 * 32];
  __shared__ unsigned short Bt[128 * 32];
  int tid = threadIdx.x;
  int w = tid >> 6, l = tid & 63, lr = l & 15, lh = l >> 4;
  int wr = w >> 1, wc = w & 1;
  int r0 = blockIdx.x * 128, c0 = blockIdx.y * 128;
  f32x4 acc[4][4] = {};
  for (int k0 = 0; k0 < 512; k0 += 32) {
#pragma unroll
    for (int p = 0; p < 2; ++p) {
      int flat = tid * 16 + p * 8;
      int row = flat >> 5, col = flat & 31;
      u32x4 va = *(const u32x4*)&A[(size_t)(r0 + row) * 512 + k0 + col];
      u32x4 vb = *(const u32x4*)&WT[(size_t)(c0 + row) * 512 + k0 + col];
      *(u32x4*)&At[swz(row, col)] = va;
      *(u32x4*)&Bt[swz(row, col)] = vb;
    }
    __syncthreads();
    bf16x8 a[4], b[4];
#pragma unroll
    for (int m = 0; m < 4; ++m)
      a[m] = *(const bf16x8*)&At[swz(wr * 64 + m * 16 + lr, lh * 8)];
#pragma unroll
    for (int n = 0; n < 4; ++n)
      b[n] = *(const bf16x8*)&Bt[swz(wc * 64 + n * 16 + lr, lh * 8)];
#pragma unroll
    for (int m = 0; m < 4; ++m)
#pragma unroll
      for (int n = 0; n < 4; ++n)
        acc[m][n] = __builtin_amdgcn_mfma_f32_16x16x32_bf16(a[m], b[n], acc[m][n], 0, 0, 0);
    __syncthreads();
  }
  int row_base = r0 + wr * 64;
  if (EPI == 0) {
    int h = (c0 + wc * 64) >> 6;
    float gq[4], bq[4];
#pragma unroll
    for (int n = 0; n < 4; ++n) { gq[n] = g[n * 16 + lr]; bq[n] = beta[n * 16 + lr]; }
#pragma unroll
    for (int m = 0; m < 4; ++m)
#pragma unroll
      for (int i = 0; i < 4; ++i) {
        float s1 = 0.f, s2 = 0.f;
#pragma unroll
        for (int n = 0; n < 4; ++n) { float v = acc[m][n][i]; s1 += v; s2 += v * v; }
#pragma unroll
        for (int off = 1; off < 16; off <<= 1) { s1 += __shfl_xor(s1, off); s2 += __shfl_xor(s2, off); }
        float mean = s1 * (1.f / 64.f);
        float var = s2 * (1.f / 64.f) - mean * mean;
        float rstd = rsqrtf(var + 1e-5f);
        int row = row_base + m * 16 + lh * 4 + i;
        int b = row >> 11, nidx = row & 2047;
        size_t obase = ((size_t)(b * HH + h) * NN + nidx) * DHH;
#pragma unroll
        for (int n = 0; n < 4; ++n) {
          float v = (acc[m][n][i] - mean) * rstd * gq[n] + bq[n];
          out_bf[obase + n * 16 + lr] = f2bf(v);
        }
      }
  } else if (EPI == 1) {
    int h = (c0 + wc * 64) >> 6;
#pragma unroll
    for (int m = 0; m < 4; ++m)
#pragma unroll
      for (int i = 0; i < 4; ++i) {
        int row = row_base + m * 16 + lh * 4 + i;
        int b = row >> 11, nidx = row & 2047;
        size_t obase = ((size_t)(b * HH + h) * NN + nidx) * DHH;
        size_t tbase = ((size_t)(b * HH + h) * DHH) * NN + nidx;
#pragma unroll
        for (int n = 0; n < 4; ++n) {
          unsigned short v = f2bf(acc[m][n][i]);
          int dh = n * 16 + lr;
          out_bf[obase + dh] = v;
          out_bf2[tbase + (size_t)dh * NN] = v;
        }
      }
  } else {
#pragma unroll
    for (int m = 0; m < 4; ++m)
#pragma unroll
      for (int i = 0; i < 4; ++i) {
        int row = row_base + m * 16 + lh * 4 + i;
#pragma unroll
        for (int n = 0; n < 4; ++n) {
          int col = c0 + wc * 64 + n * 16 + lr;
          out_f32[(size_t)row * 512 + col] = acc[m][n][i] + g[col];
        }
      }
  }
}

// ---------------- flash attention, SWAPPED operands: S^T = mfma(K,Q), O^T = mfma(VT,P)
// per (b,h), QBLK=64 (4 waves x 16 q-rows each), KVBLK=64.
// Every lane owns q-row (lr = lane&15); softmax state (m,l) is one scalar/lane.
#define SCALE_L2E (0.125f * 1.44269504088896340736f)

__global__ __launch_bounds__(256) void attn_kernel(
    const unsigned short* __restrict__ qb, const unsigned short* __restrict__ kb,
    const unsigned short* __restrict__ vtb, unsigned short* __restrict__ attn_out) {
  int qt = blockIdx.x;   // 0..31
  int bh = blockIdx.y;   // 0..31 = b*8+h
  int tid = threadIdx.x, w = tid >> 6, l = tid & 63, lr = l & 15, lh = l >> 4;
  const unsigned short* Q = qb + (size_t)bh * NN * DHH;
  const unsigned short* K = kb + (size_t)bh * NN * DHH;
  const unsigned short* VT = vtb + (size_t)bh * DHH * NN;
  int qr0 = qt * 64 + w * 16;
  // Q as B-fragment: col = lr = q-row, k-map lh*8+i (+32*kk)
  bf16x8 bq[2];
#pragma unroll
  for (int kk = 0; kk < 2; ++kk)
    bq[kk] = *(const bf16x8*)&Q[(size_t)(qr0 + lr) * DHH + lh * 8 + kk * 32];
  float mrow = -1e30f, lsum = 0.f;
  f32x4 o[4] = {};   // O^T: o[jd][i] = O[q=lr][d = jd*16 + lh*4 + i]

  __shared__ unsigned short plds[4][16 * 64];  // per-wave [q=16][k=64] bf16, XOR-swizzled
  char* pbase = (char*)&plds[w][0];
  int rowoff = lr * 128;
  int rswz = (lr & 7) << 4;

  for (int kt = 0; kt < 32; ++kt) {
    int kr0 = kt * 64;
    // ---- S^T = K · Q^T : acc[j] holds S[q=lr][k = kr0 + j*16 + lh*4 + i]
    f32x4 s[4];
#pragma unroll
    for (int j = 0; j < 4; ++j) {
      f32x4 acc = {};
#pragma unroll
      for (int kk = 0; kk < 2; ++kk) {
        bf16x8 ak = *(const bf16x8*)&K[(size_t)(kr0 + j * 16 + lr) * DHH + lh * 8 + kk * 32];
        acc = __builtin_amdgcn_mfma_f32_16x16x32_bf16(ak, bq[kk], acc, 0, 0, 0);
      }
      s[j] = acc * SCALE_L2E;   // log2-domain scores
    }
    // ---- online softmax: lane-local 16 values, 2 shuffles across lh groups
    float v01 = fmaxf(fmaxf(s[0][0], s[0][1]), fmaxf(s[0][2], s[0][3]));
    float v23 = fmaxf(fmaxf(s[1][0], s[1][1]), fmaxf(s[1][2], s[1][3]));
    float v45 = fmaxf(fmaxf(s[2][0], s[2][1]), fmaxf(s[2][2], s[2][3]));
    float v67 = fmaxf(fmaxf(s[3][0], s[3][1]), fmaxf(s[3][2], s[3][3]));
    float vmax = fmaxf(fmaxf(v01, v23), fmaxf(v45, v67));
    vmax = fmaxf(vmax, __shfl_xor(vmax, 16));
    vmax = fmaxf(vmax, __shfl_xor(vmax, 32));
    float mnew = fmaxf(mrow, vmax);
    float corr = exp2f(mrow - mnew);
    mrow = mnew;
#pragma unroll
    for (int j = 0; j < 4; ++j)
#pragma unroll
      for (int i = 0; i < 4; ++i)
        s[j][i] = exp2f(s[j][i] - mnew);
    float r01 = (s[0][0] + s[0][1]) + (s[0][2] + s[0][3]);
    float r23 = (s[1][0] + s[1][1]) + (s[1][2] + s[1][3]);
    float r45 = (s[2][0] + s[2][1]) + (s[2][2] + s[2][3]);
    float r67 = (s[3][0] + s[3][1]) + (s[3][2] + s[3][3]);
    float rsum = (r01 + r23) + (r45 + r67);
    rsum += __shfl_xor(rsum, 16);
    rsum += __shfl_xor(rsum, 32);
    lsum = lsum * corr + rsum;
#pragma unroll
    for (int jd = 0; jd < 4; ++jd)
#pragma unroll
      for (int i = 0; i < 4; ++i) o[jd][i] *= corr;
    // ---- P -> LDS: per j, 4 contiguous k -> one 8B packed write (swizzled)
#pragma unroll
    for (int j = 0; j < 4; ++j) {
      u32x2 pk;
      pk[0] = (unsigned)f2bf(s[j][0]) | ((unsigned)f2bf(s[j][1]) << 16);
      pk[1] = (unsigned)f2bf(s[j][2]) | ((unsigned)f2bf(s[j][3]) << 16);
      *(u32x2*)(pbase + rowoff + ((j * 32 + lh * 8) ^ rswz)) = pk;
    }
    // ---- P as B-fragment: [q=lr][k = lh*8 + i + 32*kk]
    bf16x8 bp[2];
#pragma unroll
    for (int kk = 0; kk < 2; ++kk)
      bp[kk] = *(const bf16x8*)(pbase + rowoff + ((lh * 16 + kk * 64) ^ rswz));
    // ---- O^T += V^T · P : A = VT (d-rows), B = P
#pragma unroll
    for (int jd = 0; jd < 4; ++jd)
#pragma unroll
      for (int kk = 0; kk < 2; ++kk) {
        bf16x8 av = *(const bf16x8*)&VT[(size_t)(jd * 16 + lr) * NN + kr0 + lh * 8 + kk * 32];
        o[jd] = __builtin_amdgcn_mfma_f32_16x16x32_bf16(av, bp[kk], o[jd], 0, 0, 0);
      }
  }
  // ---- epilogue: lane owns q-row lr; d = jd*16 + lh*4 + i contiguous per jd -> 8B stores
  int b = bh >> 3, h = bh & 7;
  float invl = 1.0f / lsum;
  size_t r = (size_t)b * NN + qr0 + lr;
#pragma unroll
  for (int jd = 0; jd < 4; ++jd) {
    u32x2 ov;
    ov[0] = (unsigned)f2bf(o[jd][0] * invl) | ((unsigned)f2bf(o[jd][1] * invl) << 16);
    ov[1] = (unsigned)f2bf(o[jd][2] * invl) | ((unsigned)f2bf(o[jd][3] * invl) << 16);
    *(u32x2*)&attn_out[r * 512 + h * 64 + jd * 16 + lh * 4] = ov;
  }
}

// ---------------- final LN over D=512 + ls scale + (b,n)->(n,b) reorder, fp32 out
__global__ __launch_bounds__(256) void lnout_kernel(
    const float* __restrict__ proj2, const float* __restrict__ g, const float* __restrict__ beta,
    const float* __restrict__ ls, float* __restrict__ out) {
  int w = threadIdx.x >> 6, l = threadIdx.x & 63;
  int row = blockIdx.x * 4 + w;   // b*2048+n
  const float* src = proj2 + (size_t)row * DD + l * 8;
  f32x4 v0 = *(const f32x4*)src;
  f32x4 v1 = *(const f32x4*)(src + 4);
  float s1 = 0.f, s2 = 0.f;
#pragma unroll
  for (int i = 0; i < 4; ++i) { s1 += v0[i] + v1[i]; s2 += v0[i] * v0[i] + v1[i] * v1[i]; }
#pragma unroll
  for (int off = 1; off < 64; off <<= 1) { s1 += __shfl_xor(s1, off); s2 += __shfl_xor(s2, off); }
  float mean = s1 * (1.f / 512.f);
  float var = s2 * (1.f / 512.f) - mean * mean;
  float rstd = rsqrtf(var + 1e-5f);
  int b = row >> 11, n = row & 2047;
  float* dst = out + ((size_t)n * BB + b) * DD + l * 8;
  f32x4 r0, r1;
#pragma unroll
  for (int i = 0; i < 4; ++i) {
    int c = l * 8 + i;
    r0[i] = ((v0[i] - mean) * rstd * g[c] + beta[c]) * ls[c];
    int c2 = c + 4;
    r1[i] = ((v1[i] - mean) * rstd * g[c2] + beta[c2]) * ls[c2];
  }
  *(f32x4*)dst = r0;
  *(f32x4*)(dst + 4) = r1;
}

extern "C" void kernel_launch(void* const* d_in, const int* in_sizes, int n_in,
                              void* d_out, int out_size, void* d_ws, size_t ws_size,
                              hipStream_t stream) {
  const float* x = (const float*)d_in[0];
  const float* kv = (const float*)d_in[1];
  const float* Wq = (const float*)d_in[2];
  const float* Wkv = (const float*)d_in[3];
  const float* lnqg = (const float*)d_in[4];
  const float* lnqb = (const float*)d_in[5];
  const float* Wo = (const float*)d_in[6];
  const float* bo = (const float*)d_in[7];
  const float* lnog = (const float*)d_in[8];
  const float* lnob = (const float*)d_in[9];
  const float* ls = (const float*)d_in[10];
  float* out = (float*)d_out;

  unsigned short* xb = (unsigned short*)d_ws;
  unsigned short* kvb = xb + (size_t)RR * DD;
  unsigned short* WqT = kvb + (size_t)RR * DD;
  unsigned short* WkvT = WqT + 512 * 512;
  unsigned short* WoT = WkvT + 512 * 512;
  unsigned short* qln = WoT + 512 * 512;          // [b][h][n][64]
  unsigned short* kvp = qln + (size_t)RR * DD;    // [b][h][m][64]
  unsigned short* kvpT = kvp + (size_t)RR * DD;   // [b][h][64][m]
  unsigned short* aout = kvpT + (size_t)RR * DD;  // [b*2048+n][512]
  float* proj2 = (float*)(aout + (size_t)RR * DD);

  cast_in_kernel<<<dim3(2048, 2), 256, 0, stream>>>(x, kv, xb, kvb);
  cast_w_kernel<<<dim3(1024, 3), 256, 0, stream>>>(Wq, Wkv, Wo, WqT, WkvT, WoT);
  gemm_kernel<0><<<dim3(64, 4), 256, 0, stream>>>(xb, WqT, lnqg, lnqb, qln, nullptr, nullptr);
  gemm_kernel<1><<<dim3(64, 4), 256, 0, stream>>>(kvb, WkvT, nullptr, nullptr, kvp, kvpT, nullptr);
  attn_kernel<<<dim3(32, 32), 256, 0, stream>>>(qln, kvp, kvpT, aout);
  gemm_kernel<2><<<dim3(64, 4), 256, 0, stream>>>(aout, WoT, bo, nullptr, nullptr, nullptr, proj2);
  lnout_kernel<<<dim3(2048), 256, 0, stream>>>(proj2, lnog, lnob, ls, out);
}

// Round 5
// 166.124 us; speedup vs baseline: 1.8216x; 1.8216x over previous
//
#include <hip/hip_runtime.h>

#define NN 2048
#define BB 4
#define DD 512
#define HH 8
#define DHH 64
#define RR 8192   // BB*NN

typedef __attribute__((ext_vector_type(8))) __bf16 bf16x8;
typedef __attribute__((ext_vector_type(4))) float f32x4;
typedef __attribute__((ext_vector_type(2))) unsigned int u32x2;
typedef __attribute__((ext_vector_type(4))) unsigned int u32x4;

static __device__ __forceinline__ unsigned short f2bf(float f) {
  unsigned u = __builtin_bit_cast(unsigned, f);
  u += 0x7fffu + ((u >> 16) & 1u);
  return (unsigned short)(u >> 16);
}

// async global->LDS, 16B per lane; LDS dest = uniform base + lane*16
static __device__ __forceinline__ void g2l16(const void* g, void* l) {
  __builtin_amdgcn_global_load_lds((const __attribute__((address_space(1))) unsigned int*)g,
                                   (__attribute__((address_space(3))) unsigned int*)l, 16, 0, 0);
}

// swizzled ushort index into a [rows][32] bf16 LDS tile (8-element granules)
static __device__ __forceinline__ int swz(int row, int col) {
  return (row * 32 + col) ^ (((row >> 1) & 3) << 3);
}

// ---------------- cast + reorder inputs: x,kv (N,B,D) fp32 -> [b*2048+n][D] bf16
__global__ __launch_bounds__(256) void cast_in_kernel(
    const float* __restrict__ x, const float* __restrict__ kv,
    unsigned short* __restrict__ xb, unsigned short* __restrict__ kvb) {
  const float* src = blockIdx.y ? kv : x;
  unsigned short* dst = blockIdx.y ? kvb : xb;
  int t = blockIdx.x * 256 + threadIdx.x;
  int o0 = t * 8;                       // output flat index, [b][n][d]
  int d = o0 & 511;
  int n = (o0 >> 9) & 2047;
  int b = o0 >> 20;
  const float* s = src + ((size_t)(n * BB + b) << 9) + d;
  f32x4 v0 = *(const f32x4*)s;
  f32x4 v1 = *(const f32x4*)(s + 4);
  union { unsigned short us[8]; u32x4 v; } o;
#pragma unroll
  for (int i = 0; i < 4; ++i) { o.us[i] = f2bf(v0[i]); o.us[4 + i] = f2bf(v1[i]); }
  *(u32x4*)(dst + o0) = o.v;
}

// ---------------- cast + transpose weights: W[k][o] fp32 -> WT[o][k] bf16 (512x512 each)
__global__ __launch_bounds__(256) void cast_w_kernel(
    const float* __restrict__ Wq, const float* __restrict__ Wkv, const float* __restrict__ Wo,
    unsigned short* __restrict__ WqT, unsigned short* __restrict__ WkvT, unsigned short* __restrict__ WoT) {
  const float* W = (blockIdx.y == 0) ? Wq : (blockIdx.y == 1) ? Wkv : Wo;
  unsigned short* WT = (blockIdx.y == 0) ? WqT : (blockIdx.y == 1) ? WkvT : WoT;
  int idx = blockIdx.x * 256 + threadIdx.x;  // 0..262143
  int o = idx & 511;
  int k = idx >> 9;
  WT[(size_t)o * 512 + k] = f2bf(W[(size_t)k * 512 + o]);
}

// ---------------- shared 128x128-tile GEMM, K=512, bf16 MFMA
// EPI 0: per-head LN -> q bf16 [b][h][n][64]
// EPI 1: cast -> kvp bf16 [b][h][m][64] AND kvpT bf16 [b][h][64][m]
// EPI 2: + bias -> fp32 [r][512]
template <int EPI>
__global__ __launch_bounds__(256) void gemm_kernel(
    const unsigned short* __restrict__ A,   // [8192][512] bf16
    const unsigned short* __restrict__ WT,  // [512 out][512 k] bf16
    const float* __restrict__ g,            // ln gamma (64) | bias (512)
    const float* __restrict__ beta,         // ln beta (64)
    unsigned short* __restrict__ out_bf,
    unsigned short* __restrict__ out_bf2,
    float* __restrict__ out_f32) {
  __shared__ unsigned short At[128 * 32];
  __shared__ unsigned short Bt[128 * 32];
  int tid = threadIdx.x;
  int w = tid >> 6, l = tid & 63, lr = l & 15, lh = l >> 4;
  int wr = w >> 1, wc = w & 1;
  int r0 = blockIdx.x * 128, c0 = blockIdx.y * 128;
  f32x4 acc[4][4] = {};
  for (int k0 = 0; k0 < 512; k0 += 32) {
#pragma unroll
    for (int p = 0; p < 2; ++p) {
      int flat = tid * 16 + p * 8;
      int row = flat >> 5, col = flat & 31;
      u32x4 va = *(const u32x4*)&A[(size_t)(r0 + row) * 512 + k0 + col];
      u32x4 vb = *(const u32x4*)&WT[(size_t)(c0 + row) * 512 + k0 + col];
      *(u32x4*)&At[swz(row, col)] = va;
      *(u32x4*)&Bt[swz(row, col)] = vb;
    }
    __syncthreads();
    bf16x8 a[4], b[4];
#pragma unroll
    for (int m = 0; m < 4; ++m)
      a[m] = *(const bf16x8*)&At[swz(wr * 64 + m * 16 + lr, lh * 8)];
#pragma unroll
    for (int n = 0; n < 4; ++n)
      b[n] = *(const bf16x8*)&Bt[swz(wc * 64 + n * 16 + lr, lh * 8)];
#pragma unroll
    for (int m = 0; m < 4; ++m)
#pragma unroll
      for (int n = 0; n < 4; ++n)
        acc[m][n] = __builtin_amdgcn_mfma_f32_16x16x32_bf16(a[m], b[n], acc[m][n], 0, 0, 0);
    __syncthreads();
  }
  int row_base = r0 + wr * 64;
  if (EPI == 0) {
    int h = (c0 + wc * 64) >> 6;
    float gq[4], bq[4];
#pragma unroll
    for (int n = 0; n < 4; ++n) { gq[n] = g[n * 16 + lr]; bq[n] = beta[n * 16 + lr]; }
#pragma unroll
    for (int m = 0; m < 4; ++m)
#pragma unroll
      for (int i = 0; i < 4; ++i) {
        float s1 = 0.f, s2 = 0.f;
#pragma unroll
        for (int n = 0; n < 4; ++n) { float v = acc[m][n][i]; s1 += v; s2 += v * v; }
#pragma unroll
        for (int off = 1; off < 16; off <<= 1) { s1 += __shfl_xor(s1, off); s2 += __shfl_xor(s2, off); }
        float mean = s1 * (1.f / 64.f);
        float var = s2 * (1.f / 64.f) - mean * mean;
        float rstd = rsqrtf(var + 1e-5f);
        int row = row_base + m * 16 + lh * 4 + i;
        int b = row >> 11, nidx = row & 2047;
        size_t obase = ((size_t)(b * HH + h) * NN + nidx) * DHH;
#pragma unroll
        for (int n = 0; n < 4; ++n) {
          float v = (acc[m][n][i] - mean) * rstd * gq[n] + bq[n];
          out_bf[obase + n * 16 + lr] = f2bf(v);
        }
      }
  } else if (EPI == 1) {
    int h = (c0 + wc * 64) >> 6;
#pragma unroll
    for (int m = 0; m < 4; ++m)
#pragma unroll
      for (int i = 0; i < 4; ++i) {
        int row = row_base + m * 16 + lh * 4 + i;
        int b = row >> 11, nidx = row & 2047;
        size_t obase = ((size_t)(b * HH + h) * NN + nidx) * DHH;
        size_t tbase = ((size_t)(b * HH + h) * DHH) * NN + nidx;
#pragma unroll
        for (int n = 0; n < 4; ++n) {
          unsigned short v = f2bf(acc[m][n][i]);
          int dh = n * 16 + lr;
          out_bf[obase + dh] = v;
          out_bf2[tbase + (size_t)dh * NN] = v;
        }
      }
  } else {
#pragma unroll
    for (int m = 0; m < 4; ++m)
#pragma unroll
      for (int i = 0; i < 4; ++i) {
        int row = row_base + m * 16 + lh * 4 + i;
#pragma unroll
        for (int n = 0; n < 4; ++n) {
          int col = c0 + wc * 64 + n * 16 + lr;
          out_f32[(size_t)row * 512 + col] = acc[m][n][i] + g[col];
        }
      }
  }
}

// ---------------- flash attention, swapped operands + LDS-staged K/V tiles
// block = 128 q-rows (4 waves x 32), KVBLK = 64, double-buffered K/VT staging
// via global_load_lds with pre-swizzled source addresses.
#define SCALE_L2E (0.125f * 1.44269504088896340736f)

__global__ __launch_bounds__(256) void attn_kernel(
    const unsigned short* __restrict__ qb, const unsigned short* __restrict__ kb,
    const unsigned short* __restrict__ vtb, unsigned short* __restrict__ attn_out) {
  int bid = blockIdx.x;              // 512 blocks
  int xcd = bid & 7, idx = bid >> 3;
  int bh = xcd * 4 + (idx >> 4);     // each XCD owns 4 heads -> K/V L2-resident
  int qt = idx & 15;
  int tid = threadIdx.x, w = tid >> 6, l = tid & 63, lr = l & 15, lh = l >> 4;
  const unsigned short* Q = qb + (size_t)bh * NN * DHH;
  const unsigned short* K = kb + (size_t)bh * NN * DHH;
  const unsigned short* VT = vtb + (size_t)bh * DHH * NN;
  int qr0 = qt * 128 + w * 32;
  int rswz = (lr & 7) << 4;

  __shared__ unsigned short kt_lds[2][64 * 64];  // [m-rows 64][dh 64], swizzled
  __shared__ unsigned short vt_lds[2][64 * 64];  // [d-rows 64][m 64], swizzled
  __shared__ unsigned short plds[4][32 * 64];    // per-wave [q 32][k 64], swizzled
  char* pb = (char*)&plds[w][0];

  // Q as B-fragments, two 16-col groups (g): col = q-row = qr0 + g*16 + lr
  bf16x8 bq[2][2];
#pragma unroll
  for (int g = 0; g < 2; ++g)
#pragma unroll
    for (int kk = 0; kk < 2; ++kk)
      bq[g][kk] = *(const bf16x8*)&Q[(size_t)(qr0 + g * 16 + lr) * DHH + lh * 8 + kk * 32];

  float mrow[2] = {-1e30f, -1e30f}, lsum[2] = {0.f, 0.f};
  f32x4 o[4][2] = {};   // o[jd][g][i] = O[q][d = jd*16 + lh*4 + i]

  // stage one K-tile (waves 0,1) + one VT-tile (waves 2,3) into buf
  auto stage = [&](int buf, int kt) {
    int kr0 = kt * 64;
    if (w < 2) {
      // K tile source is one contiguous 8KB block
      const char* gb = (const char*)(K + (size_t)kr0 * DHH);
      char* lb = (char*)&kt_lds[buf][0];
#pragma unroll
      for (int p = 0; p < 4; ++p) {
        int ol = (w * 4 + p) * 1024 + l * 16;
        int so = ol ^ (((ol >> 7) & 7) << 4);   // pre-swizzle source, linear LDS dest
        g2l16(gb + so, lb + (w * 4 + p) * 1024);
      }
    } else {
      const char* gb = (const char*)VT + (size_t)kr0 * 2;
      char* lb = (char*)&vt_lds[buf][0];
      int w2 = w - 2;
#pragma unroll
      for (int p = 0; p < 4; ++p) {
        int ol = (w2 * 4 + p) * 1024 + l * 16;
        int row = ol >> 7;
        int col = (ol & 127) ^ ((row & 7) << 4);
        g2l16(gb + (size_t)row * (NN * 2) + col, lb + (w2 * 4 + p) * 1024);
      }
    }
  };

  stage(0, 0);
  __syncthreads();   // compiler drains vmcnt(0) before s_barrier

  for (int kt = 0; kt < 32; ++kt) {
    int cur = kt & 1;
    if (kt < 31) stage(cur ^ 1, kt + 1);   // prefetch flies under compute
    const char* kbuf = (const char*)&kt_lds[cur][0];
    const char* vbuf = (const char*)&vt_lds[cur][0];

    // ---- S^T = K · Q^T : s[j][g][i] = S[q][k = j*16 + lh*4 + i]
    f32x4 s[4][2];
#pragma unroll
    for (int j = 0; j < 4; ++j) {
      bf16x8 ak[2];
#pragma unroll
      for (int kk = 0; kk < 2; ++kk)
        ak[kk] = *(const bf16x8*)(kbuf + (j * 16 + lr) * 128 + ((lh * 16 + kk * 64) ^ rswz));
#pragma unroll
      for (int g = 0; g < 2; ++g) {
        f32x4 acc = {};
#pragma unroll
        for (int kk = 0; kk < 2; ++kk)
          acc = __builtin_amdgcn_mfma_f32_16x16x32_bf16(ak[kk], bq[g][kk], acc, 0, 0, 0);
        s[j][g] = acc * SCALE_L2E;   // log2-domain scores
      }
    }

    // ---- online softmax (lane-local per q-row) + P -> LDS
#pragma unroll
    for (int g = 0; g < 2; ++g) {
      float v0 = fmaxf(fmaxf(s[0][g][0], s[0][g][1]), fmaxf(s[0][g][2], s[0][g][3]));
      float v1 = fmaxf(fmaxf(s[1][g][0], s[1][g][1]), fmaxf(s[1][g][2], s[1][g][3]));
      float v2 = fmaxf(fmaxf(s[2][g][0], s[2][g][1]), fmaxf(s[2][g][2], s[2][g][3]));
      float v3 = fmaxf(fmaxf(s[3][g][0], s[3][g][1]), fmaxf(s[3][g][2], s[3][g][3]));
      float vmax = fmaxf(fmaxf(v0, v1), fmaxf(v2, v3));
      vmax = fmaxf(vmax, __shfl_xor(vmax, 16));
      vmax = fmaxf(vmax, __shfl_xor(vmax, 32));
      float mnew = fmaxf(mrow[g], vmax);
      float corr = exp2f(mrow[g] - mnew);
      mrow[g] = mnew;
#pragma unroll
      for (int j = 0; j < 4; ++j)
#pragma unroll
        for (int i = 0; i < 4; ++i)
          s[j][g][i] = exp2f(s[j][g][i] - mnew);
      float r0 = (s[0][g][0] + s[0][g][1]) + (s[0][g][2] + s[0][g][3]);
      float r1 = (s[1][g][0] + s[1][g][1]) + (s[1][g][2] + s[1][g][3]);
      float r2 = (s[2][g][0] + s[2][g][1]) + (s[2][g][2] + s[2][g][3]);
      float r3 = (s[3][g][0] + s[3][g][1]) + (s[3][g][2] + s[3][g][3]);
      float rsum = (r0 + r1) + (r2 + r3);
      rsum += __shfl_xor(rsum, 16);
      rsum += __shfl_xor(rsum, 32);
      lsum[g] = lsum[g] * corr + rsum;
#pragma unroll
      for (int jd = 0; jd < 4; ++jd)
#pragma unroll
        for (int i = 0; i < 4; ++i) o[jd][g][i] *= corr;
#pragma unroll
      for (int j = 0; j < 4; ++j) {
        u32x2 pk;
        pk[0] = (unsigned)f2bf(s[j][g][0]) | ((unsigned)f2bf(s[j][g][1]) << 16);
        pk[1] = (unsigned)f2bf(s[j][g][2]) | ((unsigned)f2bf(s[j][g][3]) << 16);
        *(u32x2*)(pb + (g * 16 + lr) * 128 + ((j * 32 + lh * 8) ^ rswz)) = pk;
      }
    }

    // ---- O^T += V^T · P
    bf16x8 bp[2][2];
#pragma unroll
    for (int g = 0; g < 2; ++g)
#pragma unroll
      for (int kk = 0; kk < 2; ++kk)
        bp[g][kk] = *(const bf16x8*)(pb + (g * 16 + lr) * 128 + ((lh * 16 + kk * 64) ^ rswz));
#pragma unroll
    for (int jd = 0; jd < 4; ++jd) {
      bf16x8 av[2];
#pragma unroll
      for (int kk = 0; kk < 2; ++kk)
        av[kk] = *(const bf16x8*)(vbuf + (jd * 16 + lr) * 128 + ((lh * 16 + kk * 64) ^ rswz));
#pragma unroll
      for (int g = 0; g < 2; ++g)
#pragma unroll
        for (int kk = 0; kk < 2; ++kk)
          o[jd][g] = __builtin_amdgcn_mfma_f32_16x16x32_bf16(av[kk], bp[g][kk], o[jd][g], 0, 0, 0);
    }
    __syncthreads();   // next tile staged + this tile's reads done
  }

  // ---- epilogue: lane owns q-row; d contiguous per jd -> 8B stores
  int b = bh >> 3, h = bh & 7;
#pragma unroll
  for (int g = 0; g < 2; ++g) {
    float invl = 1.0f / lsum[g];
    size_t r = (size_t)b * NN + qr0 + g * 16 + lr;
#pragma unroll
    for (int jd = 0; jd < 4; ++jd) {
      u32x2 ov;
      ov[0] = (unsigned)f2bf(o[jd][g][0] * invl) | ((unsigned)f2bf(o[jd][g][1] * invl) << 16);
      ov[1] = (unsigned)f2bf(o[jd][g][2] * invl) | ((unsigned)f2bf(o[jd][g][3] * invl) << 16);
      *(u32x2*)&attn_out[r * 512 + h * 64 + jd * 16 + lh * 4] = ov;
    }
  }
}

// ---------------- final LN over D=512 + ls scale + (b,n)->(n,b) reorder, fp32 out
__global__ __launch_bounds__(256) void lnout_kernel(
    const float* __restrict__ proj2, const float* __restrict__ g, const float* __restrict__ beta,
    const float* __restrict__ ls, float* __restrict__ out) {
  int w = threadIdx.x >> 6, l = threadIdx.x & 63;
  int row = blockIdx.x * 4 + w;   // b*2048+n
  const float* src = proj2 + (size_t)row * DD + l * 8;
  f32x4 v0 = *(const f32x4*)src;
  f32x4 v1 = *(const f32x4*)(src + 4);
  float s1 = 0.f, s2 = 0.f;
#pragma unroll
  for (int i = 0; i < 4; ++i) { s1 += v0[i] + v1[i]; s2 += v0[i] * v0[i] + v1[i] * v1[i]; }
#pragma unroll
  for (int off = 1; off < 64; off <<= 1) { s1 += __shfl_xor(s1, off); s2 += __shfl_xor(s2, off); }
  float mean = s1 * (1.f / 512.f);
  float var = s2 * (1.f / 512.f) - mean * mean;
  float rstd = rsqrtf(var + 1e-5f);
  int b = row >> 11, n = row & 2047;
  float* dst = out + ((size_t)n * BB + b) * DD + l * 8;
  f32x4 r0, r1;
#pragma unroll
  for (int i = 0; i < 4; ++i) {
    int c = l * 8 + i;
    r0[i] = ((v0[i] - mean) * rstd * g[c] + beta[c]) * ls[c];
    int c2 = c + 4;
    r1[i] = ((v1[i] - mean) * rstd * g[c2] + beta[c2]) * ls[c2];
  }
  *(f32x4*)dst = r0;
  *(f32x4*)(dst + 4) = r1;
}

extern "C" void kernel_launch(void* const* d_in, const int* in_sizes, int n_in,
                              void* d_out, int out_size, void* d_ws, size_t ws_size,
                              hipStream_t stream) {
  const float* x = (const float*)d_in[0];
  const float* kv = (const float*)d_in[1];
  const float* Wq = (const float*)d_in[2];
  const float* Wkv = (const float*)d_in[3];
  const float* lnqg = (const float*)d_in[4];
  const float* lnqb = (const float*)d_in[5];
  const float* Wo = (const float*)d_in[6];
  const float* bo = (const float*)d_in[7];
  const float* lnog = (const float*)d_in[8];
  const float* lnob = (const float*)d_in[9];
  const float* ls = (const float*)d_in[10];
  float* out = (float*)d_out;

  unsigned short* xb = (unsigned short*)d_ws;
  unsigned short* kvb = xb + (size_t)RR * DD;
  unsigned short* WqT = kvb + (size_t)RR * DD;
  unsigned short* WkvT = WqT + 512 * 512;
  unsigned short* WoT = WkvT + 512 * 512;
  unsigned short* qln = WoT + 512 * 512;          // [b][h][n][64]
  unsigned short* kvp = qln + (size_t)RR * DD;    // [b][h][m][64]
  unsigned short* kvpT = kvp + (size_t)RR * DD;   // [b][h][64][m]
  unsigned short* aout = kvpT + (size_t)RR * DD;  // [b*2048+n][512]
  float* proj2 = (float*)(aout + (size_t)RR * DD);

  cast_in_kernel<<<dim3(2048, 2), 256, 0, stream>>>(x, kv, xb, kvb);
  cast_w_kernel<<<dim3(1024, 3), 256, 0, stream>>>(Wq, Wkv, Wo, WqT, WkvT, WoT);
  gemm_kernel<0><<<dim3(64, 4), 256, 0, stream>>>(xb, WqT, lnqg, lnqb, qln, nullptr, nullptr);
  gemm_kernel<1><<<dim3(64, 4), 256, 0, stream>>>(kvb, WkvT, nullptr, nullptr, kvp, kvpT, nullptr);
  attn_kernel<<<dim3(512), 256, 0, stream>>>(qln, kvp, kvpT, aout);
  gemm_kernel<2><<<dim3(64, 4), 256, 0, stream>>>(aout, WoT, bo, nullptr, nullptr, nullptr, proj2);
  lnout_kernel<<<dim3(2048), 256, 0, stream>>>(proj2, lnog, lnob, ls, out);
}

// Round 6
// 148.004 us; speedup vs baseline: 2.0446x; 1.1224x over previous
//
#include <hip/hip_runtime.h>

#define NN 2048
#define BB 4
#define DD 512
#define HH 8
#define DHH 64
#define RR 8192   // BB*NN

#define SCALE_L2E (0.125f * 1.44269504088896340736f)

typedef __attribute__((ext_vector_type(8))) __bf16 bf16x8;
typedef __attribute__((ext_vector_type(4))) float f32x4;
typedef __attribute__((ext_vector_type(16))) float f32x16;
typedef __attribute__((ext_vector_type(2))) unsigned int u32x2;
typedef __attribute__((ext_vector_type(4))) unsigned int u32x4;

static __device__ __forceinline__ unsigned short f2bf(float f) {
  unsigned u = __builtin_bit_cast(unsigned, f);
  u += 0x7fffu + ((u >> 16) & 1u);
  return (unsigned short)(u >> 16);
}

// packed f32 pair -> 2 bf16 (RTNE), single instruction
static __device__ __forceinline__ unsigned cvtpk(float lo, float hi) {
  unsigned r;
  asm("v_cvt_pk_bf16_f32 %0, %1, %2" : "=v"(r) : "v"(lo), "v"(hi));
  return r;
}

// async global->LDS, 16B per lane; LDS dest = uniform base + lane*16
static __device__ __forceinline__ void g2l16(const void* g, void* l) {
  __builtin_amdgcn_global_load_lds((const __attribute__((address_space(1))) unsigned int*)g,
                                   (__attribute__((address_space(3))) unsigned int*)l, 16, 0, 0);
}

// swizzled ushort index into a [rows][32] bf16 LDS tile (8-element granules)
static __device__ __forceinline__ int swz(int row, int col) {
  return (row * 32 + col) ^ (((row >> 1) & 3) << 3);
}

// ---------------- cast + reorder inputs: x,kv (N,B,D) fp32 -> [b*2048+n][D] bf16
__global__ __launch_bounds__(256) void cast_in_kernel(
    const float* __restrict__ x, const float* __restrict__ kv,
    unsigned short* __restrict__ xb, unsigned short* __restrict__ kvb) {
  const float* src = blockIdx.y ? kv : x;
  unsigned short* dst = blockIdx.y ? kvb : xb;
  int t = blockIdx.x * 256 + threadIdx.x;
  int o0 = t * 8;                       // output flat index, [b][n][d]
  int d = o0 & 511;
  int n = (o0 >> 9) & 2047;
  int b = o0 >> 20;
  const float* s = src + ((size_t)(n * BB + b) << 9) + d;
  f32x4 v0 = *(const f32x4*)s;
  f32x4 v1 = *(const f32x4*)(s + 4);
  union { unsigned short us[8]; u32x4 v; } o;
#pragma unroll
  for (int i = 0; i < 4; ++i) { o.us[i] = f2bf(v0[i]); o.us[4 + i] = f2bf(v1[i]); }
  *(u32x4*)(dst + o0) = o.v;
}

// ---------------- cast + transpose weights: W[k][o] fp32 -> WT[o][k] bf16 (512x512 each)
__global__ __launch_bounds__(256) void cast_w_kernel(
    const float* __restrict__ Wq, const float* __restrict__ Wkv, const float* __restrict__ Wo,
    unsigned short* __restrict__ WqT, unsigned short* __restrict__ WkvT, unsigned short* __restrict__ WoT) {
  const float* W = (blockIdx.y == 0) ? Wq : (blockIdx.y == 1) ? Wkv : Wo;
  unsigned short* WT = (blockIdx.y == 0) ? WqT : (blockIdx.y == 1) ? WkvT : WoT;
  int idx = blockIdx.x * 256 + threadIdx.x;  // 0..262143
  int o = idx & 511;
  int k = idx >> 9;
  WT[(size_t)o * 512 + k] = f2bf(W[(size_t)k * 512 + o]);
}

// ---------------- shared 128x128-tile GEMM, K=512, bf16 MFMA
// EPI 0: per-head LN (scaled by SCALE_L2E) -> q bf16 [b][h][n][64]
// EPI 1: cast -> kvp bf16 [b][h][m][64] AND kvpT bf16 [b][h][64][m]
// EPI 2: + bias -> fp32 [r][512]
template <int EPI>
__global__ __launch_bounds__(256) void gemm_kernel(
    const unsigned short* __restrict__ A,   // [8192][512] bf16
    const unsigned short* __restrict__ WT,  // [512 out][512 k] bf16
    const float* __restrict__ g,            // ln gamma (64) | bias (512)
    const float* __restrict__ beta,         // ln beta (64)
    unsigned short* __restrict__ out_bf,
    unsigned short* __restrict__ out_bf2,
    float* __restrict__ out_f32) {
  __shared__ unsigned short At[128 * 32];
  __shared__ unsigned short Bt[128 * 32];
  int tid = threadIdx.x;
  int w = tid >> 6, l = tid & 63, lr = l & 15, lh = l >> 4;
  int wr = w >> 1, wc = w & 1;
  int r0 = blockIdx.x * 128, c0 = blockIdx.y * 128;
  f32x4 acc[4][4] = {};
  for (int k0 = 0; k0 < 512; k0 += 32) {
#pragma unroll
    for (int p = 0; p < 2; ++p) {
      int flat = tid * 16 + p * 8;
      int row = flat >> 5, col = flat & 31;
      u32x4 va = *(const u32x4*)&A[(size_t)(r0 + row) * 512 + k0 + col];
      u32x4 vb = *(const u32x4*)&WT[(size_t)(c0 + row) * 512 + k0 + col];
      *(u32x4*)&At[swz(row, col)] = va;
      *(u32x4*)&Bt[swz(row, col)] = vb;
    }
    __syncthreads();
    bf16x8 a[4], b[4];
#pragma unroll
    for (int m = 0; m < 4; ++m)
      a[m] = *(const bf16x8*)&At[swz(wr * 64 + m * 16 + lr, lh * 8)];
#pragma unroll
    for (int n = 0; n < 4; ++n)
      b[n] = *(const bf16x8*)&Bt[swz(wc * 64 + n * 16 + lr, lh * 8)];
#pragma unroll
    for (int m = 0; m < 4; ++m)
#pragma unroll
      for (int n = 0; n < 4; ++n)
        acc[m][n] = __builtin_amdgcn_mfma_f32_16x16x32_bf16(a[m], b[n], acc[m][n], 0, 0, 0);
    __syncthreads();
  }
  int row_base = r0 + wr * 64;
  if (EPI == 0) {
    int h = (c0 + wc * 64) >> 6;
    float gq[4], bq[4];
#pragma unroll
    for (int n = 0; n < 4; ++n) { gq[n] = g[n * 16 + lr]; bq[n] = beta[n * 16 + lr]; }
#pragma unroll
    for (int m = 0; m < 4; ++m)
#pragma unroll
      for (int i = 0; i < 4; ++i) {
        float s1 = 0.f, s2 = 0.f;
#pragma unroll
        for (int n = 0; n < 4; ++n) { float v = acc[m][n][i]; s1 += v; s2 += v * v; }
#pragma unroll
        for (int off = 1; off < 16; off <<= 1) { s1 += __shfl_xor(s1, off); s2 += __shfl_xor(s2, off); }
        float mean = s1 * (1.f / 64.f);
        float var = s2 * (1.f / 64.f) - mean * mean;
        float rstd = rsqrtf(var + 1e-5f);
        int row = row_base + m * 16 + lh * 4 + i;
        int b = row >> 11, nidx = row & 2047;
        size_t obase = ((size_t)(b * HH + h) * NN + nidx) * DHH;
#pragma unroll
        for (int n = 0; n < 4; ++n) {
          float v = ((acc[m][n][i] - mean) * rstd * gq[n] + bq[n]) * SCALE_L2E;
          out_bf[obase + n * 16 + lr] = f2bf(v);
        }
      }
  } else if (EPI == 1) {
    int h = (c0 + wc * 64) >> 6;
#pragma unroll
    for (int m = 0; m < 4; ++m)
#pragma unroll
      for (int i = 0; i < 4; ++i) {
        int row = row_base + m * 16 + lh * 4 + i;
        int b = row >> 11, nidx = row & 2047;
        size_t obase = ((size_t)(b * HH + h) * NN + nidx) * DHH;
        size_t tbase = ((size_t)(b * HH + h) * DHH) * NN + nidx;
#pragma unroll
        for (int n = 0; n < 4; ++n) {
          unsigned short v = f2bf(acc[m][n][i]);
          int dh = n * 16 + lr;
          out_bf[obase + dh] = v;
          out_bf2[tbase + (size_t)dh * NN] = v;
        }
      }
  } else {
#pragma unroll
    for (int m = 0; m < 4; ++m)
#pragma unroll
      for (int i = 0; i < 4; ++i) {
        int row = row_base + m * 16 + lh * 4 + i;
#pragma unroll
        for (int n = 0; n < 4; ++n) {
          int col = c0 + wc * 64 + n * 16 + lr;
          out_f32[(size_t)row * 512 + col] = acc[m][n][i] + g[col];
        }
      }
  }
}

// ---------------- flash attention, 32x32x16 MFMA, swapped operands, LDS-staged K/V
// block = 128 q-rows (4 waves x 32), KVBLK = 64, double-buffered staging via
// global_load_lds with rotation+XOR pre-swizzled sources (conflict-free reads).
__global__ __launch_bounds__(256) void attn_kernel(
    const unsigned short* __restrict__ qb, const unsigned short* __restrict__ kb,
    const unsigned short* __restrict__ vtb, unsigned short* __restrict__ attn_out) {
  int bid = blockIdx.x;              // 512 blocks
  int xcd = bid & 7, idx = bid >> 3;
  int bh = xcd * 4 + (idx >> 4);     // each XCD owns 4 heads -> K/V L2-resident
  int qt = idx & 15;
  int tid = threadIdx.x, w = tid >> 6, l = tid & 63;
  int q = l & 31, hi = l >> 5;
  const unsigned short* Q = qb + (size_t)bh * NN * DHH;
  const unsigned short* Kp = kb + (size_t)bh * NN * DHH;
  const unsigned short* VT = vtb + (size_t)bh * DHH * NN;
  int qr0 = qt * 128 + w * 32;

  __shared__ unsigned short kt_lds[2][64 * 64];  // [k-rows 64][dh 64], rot+xor swizzled
  __shared__ unsigned short vt_lds[2][64 * 64];  // [d-rows 64][m 64], rot+xor swizzled
  __shared__ unsigned short plds[4][32 * 64];    // per-wave [q 32][k 64], rot+xor swizzled
  char* pb = (char*)&plds[w][0];

  int qrot = (q >> 3) * 32;          // (row>>3)&3 component (rows are lane&31)
  int qswz = (q & 7) << 4;

  // Q as B-fragments (pre-scaled by SCALE_L2E): col=q, k = st*16 + hi*8 + i
  bf16x8 bq[4];
#pragma unroll
  for (int st = 0; st < 4; ++st)
    bq[st] = *(const bf16x8*)&Q[(size_t)(qr0 + q) * DHH + st * 16 + hi * 8];

  float mrow = -1e30f, lsum = 0.f;
  f32x16 o0 = {}, o1 = {};           // O^T: d = dt*32 + (r&3)+8*(r>>2)+4*hi, col q

  // stage one K-tile (waves 0,1) + one VT-tile (waves 2,3) into buf.
  // physical LDS: linear; source pre-inverse-swizzled:
  //   logical c = ((cc ^ (rloc<<4)) - (chunk&3)*32) & 127
  int rloc = l >> 3;                 // 0..7 within chunk
  int ccl = (l & 7) * 16;
  auto stage = [&](int buf, int kt2) {
    int kr0 = kt2 * 64;
    if (w < 2) {
      char* lb = (char*)&kt_lds[buf][0];
      const char* gb = (const char*)(Kp + (size_t)kr0 * DHH);
#pragma unroll
      for (int p = 0; p < 4; ++p) {
        int chunk = w * 4 + p;
        int c = ((ccl ^ (rloc << 4)) - (chunk & 3) * 32) & 127;
        int r = chunk * 8 + rloc;
        g2l16(gb + r * 128 + c, lb + chunk * 1024);
      }
    } else {
      char* lb = (char*)&vt_lds[buf][0];
      const char* gb = (const char*)VT + (size_t)kr0 * 2;
      int w2 = w - 2;
#pragma unroll
      for (int p = 0; p < 4; ++p) {
        int chunk = w2 * 4 + p;
        int c = ((ccl ^ (rloc << 4)) - (chunk & 3) * 32) & 127;
        int r = chunk * 8 + rloc;
        g2l16(gb + (size_t)r * (NN * 2) + c, lb + chunk * 1024);
      }
    }
  };

  stage(0, 0);
  __syncthreads();   // barrier drains vmcnt -> tile 0 ready

  for (int kt = 0; kt < 32; ++kt) {
    int cur = kt & 1;
    if (kt < 31) stage(cur ^ 1, kt + 1);   // prefetch flies under compute
    const char* kbuf = (const char*)&kt_lds[cur][0];
    const char* vbuf = (const char*)&vt_lds[cur][0];

    // ---- S^T = K · Q^T : two 32x32 tiles (k-rows j*32..), contraction dh=64
    f32x16 s0 = {}, s1 = {};
#pragma unroll
    for (int st = 0; st < 4; ++st) {
      int colb = ((st * 32 + hi * 16 + qrot) & 127) ^ qswz;
      bf16x8 a0 = *(const bf16x8*)(kbuf + q * 128 + colb);
      bf16x8 a1 = *(const bf16x8*)(kbuf + (32 + q) * 128 + colb);
      s0 = __builtin_amdgcn_mfma_f32_32x32x16_bf16(a0, bq[st], s0, 0, 0, 0);
      s1 = __builtin_amdgcn_mfma_f32_32x32x16_bf16(a1, bq[st], s1, 0, 0, 0);
    }

    // ---- online softmax: lane owns 32 of its q-row's 64 scores (log2-domain)
    float p0 = fmaxf(s0[0], s0[1]), p1 = fmaxf(s0[2], s0[3]);
    float p2 = fmaxf(s0[4], s0[5]), p3 = fmaxf(s0[6], s0[7]);
    float p4 = fmaxf(s0[8], s0[9]), p5 = fmaxf(s0[10], s0[11]);
    float p6 = fmaxf(s0[12], s0[13]), p7 = fmaxf(s0[14], s0[15]);
#pragma unroll
    for (int i = 0; i < 2; ++i) {
      p0 = fmaxf(p0, fmaxf(s1[i * 8 + 0], s1[i * 8 + 1]));
      p2 = fmaxf(p2, fmaxf(s1[i * 8 + 2], s1[i * 8 + 3]));
      p4 = fmaxf(p4, fmaxf(s1[i * 8 + 4], s1[i * 8 + 5]));
      p6 = fmaxf(p6, fmaxf(s1[i * 8 + 6], s1[i * 8 + 7]));
    }
    float pmax = fmaxf(fmaxf(fmaxf(p0, p1), fmaxf(p2, p3)),
                       fmaxf(fmaxf(p4, p5), fmaxf(p6, p7)));
    pmax = fmaxf(pmax, __shfl_xor(pmax, 32));
    // defer-max: rescale only when max grew beyond threshold (T13)
    if (!__all(pmax - mrow <= 8.0f)) {
      float mnew = fmaxf(mrow, pmax);
      float corr = exp2f(mrow - mnew);
      o0 = o0 * corr;
      o1 = o1 * corr;
      lsum *= corr;
      mrow = mnew;
    }
#pragma unroll
    for (int i = 0; i < 16; ++i) {
      s0[i] = exp2f(s0[i] - mrow);
      s1[i] = exp2f(s1[i] - mrow);
    }
    float rs = 0.f;
#pragma unroll
    for (int i = 0; i < 16; ++i) rs += s0[i] + s1[i];
    lsum += rs;   // lane-local partial; cross-lane reduce once at end

    // ---- P -> LDS: per tile j, per quad m: k = j*32 + 8m + 4hi + {0..3}
#pragma unroll
    for (int m = 0; m < 4; ++m) {
      u32x2 w0, w1;
      w0[0] = cvtpk(s0[4 * m + 0], s0[4 * m + 1]);
      w0[1] = cvtpk(s0[4 * m + 2], s0[4 * m + 3]);
      w1[0] = cvtpk(s1[4 * m + 0], s1[4 * m + 1]);
      w1[1] = cvtpk(s1[4 * m + 2], s1[4 * m + 3]);
      int ck0 = ((m * 16 + hi * 8 + qrot) & 127) ^ qswz;
      int ck1 = ((64 + m * 16 + hi * 8 + qrot) & 127) ^ qswz;
      *(u32x2*)(pb + q * 128 + ck0) = w0;
      *(u32x2*)(pb + q * 128 + ck1) = w1;
    }

    // ---- O^T += V^T · P : A = VT rows d, B = P (col q, contraction m)
#pragma unroll
    for (int st = 0; st < 4; ++st) {
      int colb = ((st * 32 + hi * 16 + qrot) & 127) ^ qswz;
      bf16x8 bp = *(const bf16x8*)(pb + q * 128 + colb);
      bf16x8 a0 = *(const bf16x8*)(vbuf + q * 128 + colb);
      bf16x8 a1 = *(const bf16x8*)(vbuf + (32 + q) * 128 + colb);
      o0 = __builtin_amdgcn_mfma_f32_32x32x16_bf16(a0, bp, o0, 0, 0, 0);
      o1 = __builtin_amdgcn_mfma_f32_32x32x16_bf16(a1, bp, o1, 0, 0, 0);
    }
    __syncthreads();   // next tile staged + this tile's reads done
  }

  // ---- epilogue
  lsum += __shfl_xor(lsum, 32);
  float invl = 1.0f / lsum;
  int b = bh >> 3, h = bh & 7;
  size_t base = ((size_t)b * NN + qr0 + q) * 512 + h * 64;
#pragma unroll
  for (int m = 0; m < 4; ++m) {
    u32x2 ov;
    ov[0] = cvtpk(o0[4 * m + 0] * invl, o0[4 * m + 1] * invl);
    ov[1] = cvtpk(o0[4 * m + 2] * invl, o0[4 * m + 3] * invl);
    *(u32x2*)&attn_out[base + m * 8 + hi * 4] = ov;
    ov[0] = cvtpk(o1[4 * m + 0] * invl, o1[4 * m + 1] * invl);
    ov[1] = cvtpk(o1[4 * m + 2] * invl, o1[4 * m + 3] * invl);
    *(u32x2*)&attn_out[base + 32 + m * 8 + hi * 4] = ov;
  }
}

// ---------------- final LN over D=512 + ls scale + (b,n)->(n,b) reorder, fp32 out
__global__ __launch_bounds__(256) void lnout_kernel(
    const float* __restrict__ proj2, const float* __restrict__ g, const float* __restrict__ beta,
    const float* __restrict__ ls, float* __restrict__ out) {
  int w = threadIdx.x >> 6, l = threadIdx.x & 63;
  int row = blockIdx.x * 4 + w;   // b*2048+n
  const float* src = proj2 + (size_t)row * DD + l * 8;
  f32x4 v0 = *(const f32x4*)src;
  f32x4 v1 = *(const f32x4*)(src + 4);
  float s1 = 0.f, s2 = 0.f;
#pragma unroll
  for (int i = 0; i < 4; ++i) { s1 += v0[i] + v1[i]; s2 += v0[i] * v0[i] + v1[i] * v1[i]; }
#pragma unroll
  for (int off = 1; off < 64; off <<= 1) { s1 += __shfl_xor(s1, off); s2 += __shfl_xor(s2, off); }
  float mean = s1 * (1.f / 512.f);
  float var = s2 * (1.f / 512.f) - mean * mean;
  float rstd = rsqrtf(var + 1e-5f);
  int b = row >> 11, n = row & 2047;
  float* dst = out + ((size_t)n * BB + b) * DD + l * 8;
  f32x4 r0, r1;
#pragma unroll
  for (int i = 0; i < 4; ++i) {
    int c = l * 8 + i;
    r0[i] = ((v0[i] - mean) * rstd * g[c] + beta[c]) * ls[c];
    int c2 = c + 4;
    r1[i] = ((v1[i] - mean) * rstd * g[c2] + beta[c2]) * ls[c2];
  }
  *(f32x4*)dst = r0;
  *(f32x4*)(dst + 4) = r1;
}

extern "C" void kernel_launch(void* const* d_in, const int* in_sizes, int n_in,
                              void* d_out, int out_size, void* d_ws, size_t ws_size,
                              hipStream_t stream) {
  const float* x = (const float*)d_in[0];
  const float* kv = (const float*)d_in[1];
  const float* Wq = (const float*)d_in[2];
  const float* Wkv = (const float*)d_in[3];
  const float* lnqg = (const float*)d_in[4];
  const float* lnqb = (const float*)d_in[5];
  const float* Wo = (const float*)d_in[6];
  const float* bo = (const float*)d_in[7];
  const float* lnog = (const float*)d_in[8];
  const float* lnob = (const float*)d_in[9];
  const float* ls = (const float*)d_in[10];
  float* out = (float*)d_out;

  unsigned short* xb = (unsigned short*)d_ws;
  unsigned short* kvb = xb + (size_t)RR * DD;
  unsigned short* WqT = kvb + (size_t)RR * DD;
  unsigned short* WkvT = WqT + 512 * 512;
  unsigned short* WoT = WkvT + 512 * 512;
  unsigned short* qln = WoT + 512 * 512;          // [b][h][n][64]
  unsigned short* kvp = qln + (size_t)RR * DD;    // [b][h][m][64]
  unsigned short* kvpT = kvp + (size_t)RR * DD;   // [b][h][64][m]
  unsigned short* aout = kvpT + (size_t)RR * DD;  // [b*2048+n][512]
  float* proj2 = (float*)(aout + (size_t)RR * DD);

  cast_in_kernel<<<dim3(2048, 2), 256, 0, stream>>>(x, kv, xb, kvb);
  cast_w_kernel<<<dim3(1024, 3), 256, 0, stream>>>(Wq, Wkv, Wo, WqT, WkvT, WoT);
  gemm_kernel<0><<<dim3(64, 4), 256, 0, stream>>>(xb, WqT, lnqg, lnqb, qln, nullptr, nullptr);
  gemm_kernel<1><<<dim3(64, 4), 256, 0, stream>>>(kvb, WkvT, nullptr, nullptr, kvp, kvpT, nullptr);
  attn_kernel<<<dim3(512), 256, 0, stream>>>(qln, kvp, kvpT, aout);
  gemm_kernel<2><<<dim3(64, 4), 256, 0, stream>>>(aout, WoT, bo, nullptr, nullptr, nullptr, proj2);
  lnout_kernel<<<dim3(2048), 256, 0, stream>>>(proj2, lnog, lnob, ls, out);
}